// Round 2
// baseline (4870.946 us; speedup 1.0000x reference)
//
#include <hip/hip_runtime.h>

typedef __bf16 bf16x8 __attribute__((ext_vector_type(8)));
typedef float fx4 __attribute__((ext_vector_type(4)));
typedef unsigned short u16x8 __attribute__((ext_vector_type(8)));
typedef unsigned short u16x4 __attribute__((ext_vector_type(4)));

__device__ __forceinline__ unsigned short f2b(float f) {
  unsigned u = __float_as_uint(f);
  u = (u + 0x7fffu + ((u >> 16) & 1u)) >> 16;
  return (unsigned short)u;
}

__device__ __forceinline__ void gload16(const void* g, void* l) {
  __builtin_amdgcn_global_load_lds(
      (const __attribute__((address_space(1))) unsigned int*)g,
      (__attribute__((address_space(3))) unsigned int*)l, 16, 0, 0);
}

// ---------------------------------------------------------------------------
// Shared 128x128-tile bf16 MFMA GEMM (m97 structure: BK=32, 4 waves, 4x4 frags)
// MODE 1: A = gather-concat [x[row[e]] , edge_attr[e]] (bf16-cvt); +b1,leaky -> H1 (band-local)
// MODE 2: A = H1 band; epilogue atomicAdd into agg[col[e]]
// MODE 3: A = concat [x[node] , agg[node]/max(cnt,1)+ (cnt>0)*b2]; +b3,leaky -> H3 (band-local)
// MODE 4: A = H3 band; +b4 -> fp32 out (global rows)
// Bt is [N][K] bf16 (pre-transposed) so B-fragments are contiguous-k 16B loads.
// ---------------------------------------------------------------------------
template<int MODE, int K, int N>
__global__ __launch_bounds__(256)
void gemm_k(const unsigned short* __restrict__ A,
            const unsigned short* __restrict__ xb,   // optional bf16 x
            const float* __restrict__ xf,            // fp32 x
            const float* __restrict__ ea,            // fp32 edge_attr
            const float* __restrict__ agg,
            const float* __restrict__ cnt,
            const int* __restrict__ idx, int E,
            const unsigned short* __restrict__ Bt,
            const float* __restrict__ bias2,         // b2 (MODE 3 A-staging)
            const float* __restrict__ bias,
            float* __restrict__ outf,
            unsigned short* __restrict__ outb,
            int M, int base)
{
  __shared__ unsigned short Al[128 * 32];
  __shared__ unsigned short Bl[128 * 32];
  const int t = threadIdx.x;
  const int tile_n = blockIdx.x, tile_m = blockIdx.y;
  const int w = t >> 6, l = t & 63;
  const int wr = w >> 1, wc = w & 1;
  const int lr = l & 15, lk = l >> 4;   // lk*8 = k-offset of fragment

  fx4 zero = {0.f, 0.f, 0.f, 0.f};
  fx4 acc[4][4];
#pragma unroll
  for (int i = 0; i < 4; i++)
#pragma unroll
    for (int j = 0; j < 4; j++) acc[i][j] = zero;

  for (int k0 = 0; k0 < K; k0 += 32) {
#pragma unroll
    for (int it = 0; it < 2; ++it) {
      const int c = t + it * 256;          // 16B chunk id 0..511
      const int row = c >> 2, u = c & 3;
      // --- B tile ---
      gload16(Bt + (size_t)(tile_n * 128 + row) * K + (k0 + u * 8),
              (char*)Bl + c * 16);
      // --- A tile ---
      if constexpr (MODE == 1) {
        int rl = tile_m * 128 + row; if (rl >= M) rl = M - 1;
        const int e = base + rl;
        if (k0 < 256) {
          const int node = idx[e];
          if (xb) {
            gload16(xb + (size_t)node * 256 + (k0 + u * 8), (char*)Al + c * 16);
          } else {
            const float* s = xf + (size_t)node * 256 + (k0 + u * 8);
            fx4 f0 = *(const fx4*)s, f1 = *(const fx4*)(s + 4);
            u16x8 v;
            v[0]=f2b(f0[0]); v[1]=f2b(f0[1]); v[2]=f2b(f0[2]); v[3]=f2b(f0[3]);
            v[4]=f2b(f1[0]); v[5]=f2b(f1[1]); v[6]=f2b(f1[2]); v[7]=f2b(f1[3]);
            *(u16x8*)((char*)Al + c * 16) = v;
          }
        } else {
          const float* s = ea + (size_t)e * 256 + (k0 - 256) + u * 8;
          fx4 f0 = *(const fx4*)s, f1 = *(const fx4*)(s + 4);
          u16x8 v;
          v[0]=f2b(f0[0]); v[1]=f2b(f0[1]); v[2]=f2b(f0[2]); v[3]=f2b(f0[3]);
          v[4]=f2b(f1[0]); v[5]=f2b(f1[1]); v[6]=f2b(f1[2]); v[7]=f2b(f1[3]);
          *(u16x8*)((char*)Al + c * 16) = v;
        }
      } else if constexpr (MODE == 3) {
        int rl = tile_m * 128 + row; if (rl >= M) rl = M - 1;
        const int node = base + rl;
        if (k0 < 256) {
          const float* s = xf + (size_t)node * 256 + (k0 + u * 8);
          fx4 f0 = *(const fx4*)s, f1 = *(const fx4*)(s + 4);
          u16x8 v;
          v[0]=f2b(f0[0]); v[1]=f2b(f0[1]); v[2]=f2b(f0[2]); v[3]=f2b(f0[3]);
          v[4]=f2b(f1[0]); v[5]=f2b(f1[1]); v[6]=f2b(f1[2]); v[7]=f2b(f1[3]);
          *(u16x8*)((char*)Al + c * 16) = v;
        } else {
          const int j = (k0 - 256) + u * 8;
          const float ct = cnt[node];
          const float rs = 1.f / fmaxf(ct, 1.f);
          const float* ag = agg + (size_t)node * 512 + j;
          const float* bb = bias2 + j;
          u16x8 v;
#pragma unroll
          for (int q = 0; q < 8; q++)
            v[q] = f2b(ag[q] * rs + (ct > 0.f ? bb[q] : 0.f));
          *(u16x8*)((char*)Al + c * 16) = v;
        }
      } else {
        int rl = tile_m * 128 + row; if (rl >= M) rl = M - 1;
        gload16(A + (size_t)rl * K + (k0 + u * 8), (char*)Al + c * 16);
      }
    }
    __syncthreads();   // drains vmcnt (global_load_lds) + lgkm (ds_write)

    bf16x8 af[4], bfr[4];
    const int mb0 = wr * 64, nb0 = wc * 64;
#pragma unroll
    for (int i = 0; i < 4; i++)
      af[i] = *(const bf16x8*)(Al + (mb0 + i * 16 + lr) * 32 + lk * 8);
#pragma unroll
    for (int j = 0; j < 4; j++)
      bfr[j] = *(const bf16x8*)(Bl + (nb0 + j * 16 + lr) * 32 + lk * 8);
#pragma unroll
    for (int i = 0; i < 4; i++)
#pragma unroll
      for (int j = 0; j < 4; j++)
        acc[i][j] = __builtin_amdgcn_mfma_f32_16x16x32_bf16(af[i], bfr[j],
                                                            acc[i][j], 0, 0, 0);
    __syncthreads();
  }

  // Epilogue. C/D layout: col = lane&15, row = (lane>>4)*4 + reg  [m89]
#pragma unroll
  for (int j = 0; j < 4; j++) {
    const int n = tile_n * 128 + wc * 64 + j * 16 + lr;
    float bj = 0.f;
    if constexpr (MODE != 2) bj = bias[n];
#pragma unroll
    for (int i = 0; i < 4; i++) {
      const int m0 = tile_m * 128 + wr * 64 + i * 16 + lk * 4;
#pragma unroll
      for (int r = 0; r < 4; r++) {
        const int m = m0 + r;
        if (m < M) {
          float v = acc[i][j][r];
          if constexpr (MODE == 2) {
            const int cn = idx[E + base + m];     // destination node
            atomicAdd(outf + (size_t)cn * N + n, v);
          } else if constexpr (MODE == 4) {
            outf[(size_t)(base + m) * N + n] = v + bj;
          } else {
            v += bj;
            v = v >= 0.f ? v : 0.01f * v;
            outb[(size_t)m * N + n] = f2b(v);
          }
        }
      }
    }
  }
}

// ---------------------------------------------------------------------------
// Helper kernels
// ---------------------------------------------------------------------------
// edge_index may arrive as int64 (reference dtype) or int32. Detect: int64
// nonneg values < 2^31 have all odd 32-bit words == 0. Repack to int32.
__global__ void fix_idx_k(const int* __restrict__ src, int* __restrict__ dst, int n2) {
  int i = blockIdx.x * blockDim.x + threadIdx.x;
  if (i >= n2) return;
  bool is64 = true;
#pragma unroll
  for (int p = 0; p < 16; ++p) is64 = is64 && (src[2 * p + 1] == 0);
  dst[i] = is64 ? src[2 * i] : src[i];
}

__global__ void cvt_x_k(const float* __restrict__ x, unsigned short* __restrict__ xbo,
                        int n4) {
  int i = blockIdx.x * blockDim.x + threadIdx.x;
  if (i < n4) {
    fx4 f = *(const fx4*)(x + (size_t)i * 4);
    u16x4 v; v[0]=f2b(f[0]); v[1]=f2b(f[1]); v[2]=f2b(f[2]); v[3]=f2b(f[3]);
    *(u16x4*)(xbo + (size_t)i * 4) = v;
  }
}

// W[K][N] fp32 -> Wt[N][K] bf16
__global__ void cvt_w_k(const float* __restrict__ W, unsigned short* __restrict__ Wt,
                        int K, int N) {
  long i = (long)blockIdx.x * blockDim.x + threadIdx.x;
  if (i < (long)K * N) {
    int k = (int)(i / N), n = (int)(i % N);
    Wt[(size_t)n * K + k] = f2b(W[i]);
  }
}

__global__ void cnt_kk(const int* __restrict__ ecol, float* __restrict__ cnt, int E) {
  int i = blockIdx.x * blockDim.x + threadIdx.x;
  if (i < E) atomicAdd(cnt + ecol[i], 1.f);
}

// ---------------------------------------------------------------------------
extern "C" void kernel_launch(void* const* d_in, const int* in_sizes, int n_in,
                              void* d_out, int out_size, void* d_ws, size_t ws_size,
                              hipStream_t stream)
{
  const float* x  = (const float*)d_in[0];
  const int* eraw = (const int*)d_in[1];
  const float* ea = (const float*)d_in[2];
  const float* W1 = (const float*)d_in[5];
  const float* b1 = (const float*)d_in[6];
  const float* W2 = (const float*)d_in[7];
  const float* b2 = (const float*)d_in[8];
  const float* W3 = (const float*)d_in[9];
  const float* b3 = (const float*)d_in[10];
  const float* W4 = (const float*)d_in[11];
  const float* b4 = (const float*)d_in[12];
  float* out = (float*)d_out;

  const int Nn = in_sizes[0] / 256;   // 50000 nodes
  const int E  = in_sizes[1] / 2;     // 500000 edges

  // ---- workspace carve (256B-aligned bump allocator) ----
  char* p = (char*)d_ws;
  auto take = [&](size_t bytes) -> char* {
    char* r = p; p += (bytes + 255) & ~(size_t)255; return r;
  };
  unsigned short* W1t = (unsigned short*)take((size_t)512 * 1024 * 2);
  unsigned short* W2t = (unsigned short*)take((size_t)1024 * 512 * 2);
  unsigned short* W3t = (unsigned short*)take((size_t)768 * 1536 * 2);
  unsigned short* W4t = (unsigned short*)take((size_t)1536 * 256 * 2);
  int* idx  = (int*)take((size_t)2 * E * 4);
  float* agg = (float*)take((size_t)Nn * 512 * 4);
  float* cnt = (float*)take((size_t)Nn * 4);
  size_t zlen = (size_t)(p - (char*)agg);         // agg+cnt zero region

  long avail = (long)ws_size - (long)(p - (char*)d_ws);

  unsigned short* xb = nullptr;
  const long xb_bytes = ((long)Nn * 256 * 2 + 255) & ~255L;
  if (avail >= xb_bytes + (4L << 20) + 128 * 2048 + 128 * 3072) {
    xb = (unsigned short*)take((size_t)Nn * 256 * 2);
    avail -= xb_bytes;
  }

  long bandE = (avail * 2 / 5) / 2048;  bandE &= ~127L;
  if (bandE > 32768) bandE = 32768;
  if (bandE < 128)   bandE = 128;
  long bandN = (avail - bandE * 2048) / 3072;  bandN &= ~127L;
  if (bandN > 50048) bandN = 50048;
  if (bandN < 128)   bandN = 128;
  while (bandE * 2048 + bandN * 3072 + 512 > avail && bandN > 128) bandN -= 128;
  while (bandE * 2048 + bandN * 3072 + 512 > avail && bandE > 128) bandE -= 128;
  unsigned short* H1 = (unsigned short*)take((size_t)bandE * 2048);
  unsigned short* H3 = (unsigned short*)take((size_t)bandN * 3072);

  hipMemsetAsync(agg, 0, zlen, stream);
  fix_idx_k<<<(2 * E + 255) / 256, 256, 0, stream>>>(eraw, idx, 2 * E);
  if (xb) cvt_x_k<<<(Nn * 64 + 255) / 256, 256, 0, stream>>>(x, xb, Nn * 64);
  cvt_w_k<<<(512 * 1024 + 255) / 256, 256, 0, stream>>>(W1, W1t, 512, 1024);
  cvt_w_k<<<(1024 * 512 + 255) / 256, 256, 0, stream>>>(W2, W2t, 1024, 512);
  cvt_w_k<<<(768 * 1536 + 255) / 256, 256, 0, stream>>>(W3, W3t, 768, 1536);
  cvt_w_k<<<(1536 * 256 + 255) / 256, 256, 0, stream>>>(W4, W4t, 1536, 256);
  cnt_kk<<<(E + 255) / 256, 256, 0, stream>>>(idx + E, cnt, E);  // DEST counts

  // edge MLP, banded over edges
  for (long base = 0; base < E; base += bandE) {
    long rem = E - base;
    int mb = (int)(rem < bandE ? rem : bandE);
    int mt = (mb + 127) / 128;
    gemm_k<1, 512, 1024><<<dim3(8, mt), 256, 0, stream>>>(
        nullptr, xb, x, ea, nullptr, nullptr, idx, E, W1t, nullptr, b1,
        nullptr, H1, mb, (int)base);
    gemm_k<2, 1024, 512><<<dim3(4, mt), 256, 0, stream>>>(
        H1, nullptr, nullptr, nullptr, nullptr, nullptr, idx, E, W2t, nullptr,
        nullptr, agg, nullptr, mb, (int)base);
  }

  // node MLP, banded over nodes (A-tile staged straight from x/agg/cnt)
  for (long base = 0; base < Nn; base += bandN) {
    long rem = Nn - base;
    int mb = (int)(rem < bandN ? rem : bandN);
    int mt = (mb + 127) / 128;
    gemm_k<3, 768, 1536><<<dim3(12, mt), 256, 0, stream>>>(
        nullptr, nullptr, x, nullptr, agg, cnt, nullptr, 0, W3t, b2, b3,
        nullptr, H3, mb, (int)base);
    gemm_k<4, 1536, 256><<<dim3(2, mt), 256, 0, stream>>>(
        H3, nullptr, nullptr, nullptr, nullptr, nullptr, nullptr, 0, W4t,
        nullptr, b4, out, nullptr, mb, (int)base);
  }
}

// Round 3
// 3163.894 us; speedup vs baseline: 1.5395x; 1.5395x over previous
//
#include <hip/hip_runtime.h>

typedef __bf16 bf16x8 __attribute__((ext_vector_type(8)));
typedef float fx4 __attribute__((ext_vector_type(4)));
typedef unsigned short u16x8 __attribute__((ext_vector_type(8)));
typedef unsigned short u16x4 __attribute__((ext_vector_type(4)));

__device__ __forceinline__ unsigned short f2b(float f) {
  unsigned u = __float_as_uint(f);
  u = (u + 0x7fffu + ((u >> 16) & 1u)) >> 16;
  return (unsigned short)u;
}

__device__ __forceinline__ void gload16(const void* g, void* l) {
  __builtin_amdgcn_global_load_lds(
      (const __attribute__((address_space(1))) unsigned int*)g,
      (__attribute__((address_space(3))) unsigned int*)l, 16, 0, 0);
}

// ---------------------------------------------------------------------------
// 128x128-tile bf16 MFMA GEMM (m97 structure), 4 modes:
// MODE 1 (G1): A = gather-concat [xb[row[e]] , ea[e]] ; +b1, leaky;
//              epilogue: atomicAdd into aggH[dest[e]][n]  (layer2 hoisted out!)
// MODE 2 (A2): A = bf16(aggH[node]/max(cnt,1)); + (cnt>0)*b2 -> agg2b bf16
// MODE 3 (G3): A = concat [xb[node] , agg2b[node]]; +b3, leaky -> H3 bf16
// MODE 4 (G4): A = H3 band; +b4 -> fp32 out (rows base+m)
// Bt is [N][K] bf16 pre-transposed.
// ---------------------------------------------------------------------------
template<int MODE, int K, int N, bool EAB>
__global__ __launch_bounds__(256)
void gemm_k(const unsigned short* __restrict__ A,        // mode4: H3
            const unsigned short* __restrict__ xb,       // bf16 x
            const unsigned short* __restrict__ eab,      // bf16 edge_attr (opt)
            const float* __restrict__ eaf,               // fp32 edge_attr
            const float* __restrict__ aggH_in,           // mode2 A source
            const float* __restrict__ cnt,
            const unsigned short* __restrict__ agg2b_in, // mode3 A source k>=256
            const int* __restrict__ idx, int E,
            const unsigned short* __restrict__ Bt,
            const float* __restrict__ bias,
            float* __restrict__ outf,                    // mode1: aggH ; mode4: out
            unsigned short* __restrict__ outb,           // mode2: agg2b ; mode3: H3
            int M, int base)
{
  __shared__ unsigned short Al[128 * 32];
  __shared__ unsigned short Bl[128 * 32];
  const int t = threadIdx.x;
  const int tile_n = blockIdx.x, tile_m = blockIdx.y;
  const int w = t >> 6, l = t & 63;
  const int wr = w >> 1, wc = w & 1;
  const int lr = l & 15, lk = l >> 4;

  fx4 zero = {0.f, 0.f, 0.f, 0.f};
  fx4 acc[4][4];
#pragma unroll
  for (int i = 0; i < 4; i++)
#pragma unroll
    for (int j = 0; j < 4; j++) acc[i][j] = zero;

  for (int k0 = 0; k0 < K; k0 += 32) {
#pragma unroll
    for (int it = 0; it < 2; ++it) {
      const int c = t + it * 256;          // 16B chunk id 0..511
      const int row = c >> 2, u = c & 3;
      gload16(Bt + (size_t)(tile_n * 128 + row) * K + (k0 + u * 8),
              (char*)Bl + c * 16);
      int rl = tile_m * 128 + row; if (rl >= M) rl = M - 1;
      if constexpr (MODE == 1) {
        const int e = rl;
        if (k0 < 256) {
          const int node = idx[e];
          gload16(xb + (size_t)node * 256 + (k0 + u * 8), (char*)Al + c * 16);
        } else if constexpr (EAB) {
          gload16(eab + (size_t)e * 256 + (k0 - 256) + u * 8, (char*)Al + c * 16);
        } else {
          const float* s = eaf + (size_t)e * 256 + (k0 - 256) + u * 8;
          fx4 f0 = *(const fx4*)s, f1 = *(const fx4*)(s + 4);
          u16x8 v;
          v[0]=f2b(f0[0]); v[1]=f2b(f0[1]); v[2]=f2b(f0[2]); v[3]=f2b(f0[3]);
          v[4]=f2b(f1[0]); v[5]=f2b(f1[1]); v[6]=f2b(f1[2]); v[7]=f2b(f1[3]);
          *(u16x8*)((char*)Al + c * 16) = v;
        }
      } else if constexpr (MODE == 2) {
        const int node = rl;
        const float ct = cnt[node];
        const float rs = 1.f / fmaxf(ct, 1.f);
        const float* s = aggH_in + (size_t)node * 1024 + (k0 + u * 8);
        fx4 f0 = *(const fx4*)s, f1 = *(const fx4*)(s + 4);
        u16x8 v;
        v[0]=f2b(f0[0]*rs); v[1]=f2b(f0[1]*rs); v[2]=f2b(f0[2]*rs); v[3]=f2b(f0[3]*rs);
        v[4]=f2b(f1[0]*rs); v[5]=f2b(f1[1]*rs); v[6]=f2b(f1[2]*rs); v[7]=f2b(f1[3]*rs);
        *(u16x8*)((char*)Al + c * 16) = v;
      } else if constexpr (MODE == 3) {
        const int node = base + rl;
        if (k0 < 256)
          gload16(xb + (size_t)node * 256 + (k0 + u * 8), (char*)Al + c * 16);
        else
          gload16(agg2b_in + (size_t)node * 512 + (k0 - 256) + u * 8,
                  (char*)Al + c * 16);
      } else {
        gload16(A + (size_t)rl * K + (k0 + u * 8), (char*)Al + c * 16);
      }
    }
    __syncthreads();

    bf16x8 af[4], bfr[4];
    const int mb0 = wr * 64, nb0 = wc * 64;
#pragma unroll
    for (int i = 0; i < 4; i++)
      af[i] = *(const bf16x8*)(Al + (mb0 + i * 16 + lr) * 32 + lk * 8);
#pragma unroll
    for (int j = 0; j < 4; j++)
      bfr[j] = *(const bf16x8*)(Bl + (nb0 + j * 16 + lr) * 32 + lk * 8);
#pragma unroll
    for (int i = 0; i < 4; i++)
#pragma unroll
      for (int j = 0; j < 4; j++)
        acc[i][j] = __builtin_amdgcn_mfma_f32_16x16x32_bf16(af[i], bfr[j],
                                                            acc[i][j], 0, 0, 0);
    __syncthreads();
  }

  // Epilogue. C/D layout: col = lane&15, row = (lane>>4)*4 + reg  [m89]
#pragma unroll
  for (int j = 0; j < 4; j++) {
    const int n = tile_n * 128 + wc * 64 + j * 16 + lr;
    const float bj = bias[n];
#pragma unroll
    for (int i = 0; i < 4; i++) {
      const int m0 = tile_m * 128 + wr * 64 + i * 16 + lk * 4;
#pragma unroll
      for (int r = 0; r < 4; r++) {
        const int m = m0 + r;
        if (m < M) {
          float v = acc[i][j][r];
          if constexpr (MODE == 1) {
            v += bj;
            v = v >= 0.f ? v : 0.01f * v;
            const int dest = idx[E + m];
            atomicAdd(outf + (size_t)dest * 1024 + n, v);
          } else if constexpr (MODE == 2) {
            v += (cnt[m] > 0.f ? bj : 0.f);
            outb[(size_t)m * N + n] = f2b(v);
          } else if constexpr (MODE == 3) {
            v += bj;
            v = v >= 0.f ? v : 0.01f * v;
            outb[(size_t)m * N + n] = f2b(v);
          } else {
            outf[(size_t)(base + m) * N + n] = v + bj;
          }
        }
      }
    }
  }
}

// ---------------------------------------------------------------------------
// Helper kernels
// ---------------------------------------------------------------------------
__global__ void fix_idx_k(const int* __restrict__ src, int* __restrict__ dst, int n2) {
  int i = blockIdx.x * blockDim.x + threadIdx.x;
  if (i >= n2) return;
  bool is64 = true;
#pragma unroll
  for (int p = 0; p < 16; ++p) is64 = is64 && (src[2 * p + 1] == 0);
  dst[i] = is64 ? src[2 * i] : src[i];
}

__global__ void cvt_f2b_k(const float* __restrict__ x, unsigned short* __restrict__ o,
                          long n4) {
  long i = (long)blockIdx.x * blockDim.x + threadIdx.x;
  if (i < n4) {
    fx4 f = *(const fx4*)(x + i * 4);
    u16x4 v; v[0]=f2b(f[0]); v[1]=f2b(f[1]); v[2]=f2b(f[2]); v[3]=f2b(f[3]);
    *(u16x4*)(o + i * 4) = v;
  }
}

// W[K][N] fp32 -> Wt[N][K] bf16
__global__ void cvt_w_k(const float* __restrict__ W, unsigned short* __restrict__ Wt,
                        int K, int N) {
  long i = (long)blockIdx.x * blockDim.x + threadIdx.x;
  if (i < (long)K * N) {
    int k = (int)(i / N), n = (int)(i % N);
    Wt[(size_t)n * K + k] = f2b(W[i]);
  }
}

__global__ void cnt_kk(const int* __restrict__ ecol, float* __restrict__ cnt, int E) {
  int i = blockIdx.x * blockDim.x + threadIdx.x;
  if (i < E) atomicAdd(cnt + ecol[i], 1.f);
}

// ---------------------------------------------------------------------------
extern "C" void kernel_launch(void* const* d_in, const int* in_sizes, int n_in,
                              void* d_out, int out_size, void* d_ws, size_t ws_size,
                              hipStream_t stream)
{
  const float* x  = (const float*)d_in[0];
  const int* eraw = (const int*)d_in[1];
  const float* ea = (const float*)d_in[2];
  const float* W1 = (const float*)d_in[5];
  const float* b1 = (const float*)d_in[6];
  const float* W2 = (const float*)d_in[7];
  const float* b2 = (const float*)d_in[8];
  const float* W3 = (const float*)d_in[9];
  const float* b3 = (const float*)d_in[10];
  const float* W4 = (const float*)d_in[11];
  const float* b4 = (const float*)d_in[12];
  float* out = (float*)d_out;

  const int Nn = in_sizes[0] / 256;   // 50000
  const int E  = in_sizes[1] / 2;     // 500000

  // ---- workspace carve (256B-aligned bump allocator) ----
  char* p = (char*)d_ws;
  auto take = [&](size_t bytes) -> char* {
    char* r = p; p += (bytes + 255) & ~(size_t)255; return r;
  };
  unsigned short* W1t = (unsigned short*)take((size_t)512 * 1024 * 2);
  unsigned short* W2t = (unsigned short*)take((size_t)1024 * 512 * 2);
  unsigned short* W3t = (unsigned short*)take((size_t)768 * 1536 * 2);
  unsigned short* W4t = (unsigned short*)take((size_t)1536 * 256 * 2);
  int* idx  = (int*)take((size_t)2 * E * 4);
  float* cnt  = (float*)take((size_t)Nn * 4);
  float* aggH = (float*)take((size_t)Nn * 1024 * 4);      // layer-1 scatter-sum
  size_t zlen = (size_t)(p - (char*)cnt);                 // cnt+aggH zero region
  unsigned short* agg2b = (unsigned short*)take((size_t)Nn * 512 * 2);
  unsigned short* xb    = (unsigned short*)take((size_t)Nn * 256 * 2);

  long avail = (long)ws_size - (long)(p - (char*)d_ws);

  unsigned short* eab = nullptr;                          // optional bf16 edge_attr
  const long eab_bytes = (((long)E * 256 * 2) + 255) & ~255L;
  if (avail >= eab_bytes + 128 * 3072 + 1024) {
    eab = (unsigned short*)take((size_t)E * 256 * 2);
    avail -= eab_bytes;
  }
  long bandN = avail / 3072;  bandN &= ~127L;
  if (bandN > 50048) bandN = 50048;
  if (bandN < 128)   bandN = 128;
  unsigned short* H3 = (unsigned short*)take((size_t)bandN * 3072);

  hipMemsetAsync(cnt, 0, zlen, stream);
  fix_idx_k<<<(2 * E + 255) / 256, 256, 0, stream>>>(eraw, idx, 2 * E);
  cnt_kk<<<(E + 255) / 256, 256, 0, stream>>>(idx + E, cnt, E);   // dest counts
  cvt_f2b_k<<<(Nn * 64 + 255) / 256, 256, 0, stream>>>(x, xb, (long)Nn * 64);
  if (eab)
    cvt_f2b_k<<<(int)(((long)E * 64 + 255) / 256), 256, 0, stream>>>(ea, eab,
                                                                     (long)E * 64);
  cvt_w_k<<<(512 * 1024 + 255) / 256, 256, 0, stream>>>(W1, W1t, 512, 1024);
  cvt_w_k<<<(1024 * 512 + 255) / 256, 256, 0, stream>>>(W2, W2t, 1024, 512);
  cvt_w_k<<<(768 * 1536 + 255) / 256, 256, 0, stream>>>(W3, W3t, 768, 1536);
  cvt_w_k<<<(1536 * 256 + 255) / 256, 256, 0, stream>>>(W4, W4t, 1536, 256);

  // G1: edge layer-1 + fused scatter-add into aggH (single dispatch)
  const int mtE = (E + 127) / 128;
  if (eab)
    gemm_k<1, 512, 1024, true><<<dim3(8, mtE), 256, 0, stream>>>(
        nullptr, xb, eab, ea, nullptr, nullptr, nullptr, idx, E, W1t, b1,
        aggH, nullptr, E, 0);
  else
    gemm_k<1, 512, 1024, false><<<dim3(8, mtE), 256, 0, stream>>>(
        nullptr, xb, nullptr, ea, nullptr, nullptr, nullptr, idx, E, W1t, b1,
        aggH, nullptr, E, 0);

  // A2: agg2 = (aggH/max(cnt,1)) @ W2 + (cnt>0)*b2   [hoisted layer 2]
  const int mtN = (Nn + 127) / 128;
  gemm_k<2, 1024, 512, false><<<dim3(4, mtN), 256, 0, stream>>>(
      nullptr, nullptr, nullptr, nullptr, aggH, cnt, nullptr, nullptr, 0, W2t,
      b2, nullptr, agg2b, Nn, 0);

  // node MLP, banded over nodes
  for (long base = 0; base < Nn; base += bandN) {
    long rem = Nn - base;
    int mb = (int)(rem < bandN ? rem : bandN);
    int mt = (mb + 127) / 128;
    gemm_k<3, 768, 1536, false><<<dim3(12, mt), 256, 0, stream>>>(
        nullptr, xb, nullptr, nullptr, nullptr, nullptr, agg2b, nullptr, 0,
        W3t, b3, nullptr, H3, mb, (int)base);
    gemm_k<4, 1536, 256, false><<<dim3(2, mt), 256, 0, stream>>>(
        H3, nullptr, nullptr, nullptr, nullptr, nullptr, nullptr, nullptr, 0,
        W4t, b4, out, nullptr, mb, (int)base);
  }
}

// Round 4
// 2185.250 us; speedup vs baseline: 2.2290x; 1.4478x over previous
//
#include <hip/hip_runtime.h>

typedef __bf16 bf16x8 __attribute__((ext_vector_type(8)));
typedef float fx4 __attribute__((ext_vector_type(4)));
typedef unsigned short u16x8 __attribute__((ext_vector_type(8)));
typedef unsigned short u16x4 __attribute__((ext_vector_type(4)));

__device__ __forceinline__ unsigned short f2b(float f) {
  unsigned u = __float_as_uint(f);
  u = (u + 0x7fffu + ((u >> 16) & 1u)) >> 16;
  return (unsigned short)u;
}

__device__ __forceinline__ void gload16(const void* g, void* l) {
  __builtin_amdgcn_global_load_lds(
      (const __attribute__((address_space(1))) unsigned int*)g,
      (__attribute__((address_space(3))) unsigned int*)l, 16, 0, 0);
}

// ---------------------------------------------------------------------------
// 128x128-tile bf16 MFMA GEMM (m97 structure), 4 modes:
// MODE 1 (G1): rows = dest-sorted edges. A = [xb[ssrc[s]] , ea[perm[s]]];
//              +b1, leaky; epilogue: run-merged atomicAdd into aggH[sdst[s]][n]
// MODE 2 (A2): A = bf16(aggH[node]/max(cnt,1)); + (cnt>0)*b2 -> agg2b bf16
// MODE 3 (G3): A = concat [xb[node] , agg2b[node]]; +b3, leaky -> H3 bf16
// MODE 4 (G4): A = H3 band; +b4 -> fp32 out (rows base+m)
// Bt is [N][K] bf16 pre-transposed.
// ---------------------------------------------------------------------------
template<int MODE, int K, int N, bool EAB>
__global__ __launch_bounds__(256)
void gemm_k(const unsigned short* __restrict__ A,        // mode4: H3
            const unsigned short* __restrict__ xb,       // bf16 x
            const unsigned short* __restrict__ eab,      // bf16 edge_attr (opt)
            const float* __restrict__ eaf,               // fp32 edge_attr
            const float* __restrict__ aggH_in,           // mode2 A source
            const float* __restrict__ cnt,
            const unsigned short* __restrict__ agg2b_in, // mode3 A source k>=256
            const int* __restrict__ perm,                // sorted->orig edge
            const int* __restrict__ ssrc,                // sorted src node
            const int* __restrict__ sdst,                // sorted dest node
            const unsigned short* __restrict__ Bt,
            const float* __restrict__ bias,
            float* __restrict__ outf,                    // mode1: aggH ; mode4: out
            unsigned short* __restrict__ outb,           // mode2: agg2b ; mode3: H3
            int M, int base)
{
  __shared__ unsigned short Al[128 * 32];
  __shared__ unsigned short Bl[128 * 32];
  const int t = threadIdx.x;
  const int tile_n = blockIdx.x, tile_m = blockIdx.y;
  const int w = t >> 6, l = t & 63;
  const int wr = w >> 1, wc = w & 1;
  const int lr = l & 15, lk = l >> 4;

  fx4 zero = {0.f, 0.f, 0.f, 0.f};
  fx4 acc[4][4];
#pragma unroll
  for (int i = 0; i < 4; i++)
#pragma unroll
    for (int j = 0; j < 4; j++) acc[i][j] = zero;

  for (int k0 = 0; k0 < K; k0 += 32) {
#pragma unroll
    for (int it = 0; it < 2; ++it) {
      const int c = t + it * 256;          // 16B chunk id 0..511
      const int row = c >> 2, u = c & 3;
      gload16(Bt + (size_t)(tile_n * 128 + row) * K + (k0 + u * 8),
              (char*)Bl + c * 16);
      int rl = tile_m * 128 + row; if (rl >= M) rl = M - 1;
      if constexpr (MODE == 1) {
        if (k0 < 256) {
          const int node = ssrc[rl];
          gload16(xb + (size_t)node * 256 + (k0 + u * 8), (char*)Al + c * 16);
        } else {
          const int e = perm[rl];
          if constexpr (EAB) {
            gload16(eab + (size_t)e * 256 + (k0 - 256) + u * 8,
                    (char*)Al + c * 16);
          } else {
            const float* s = eaf + (size_t)e * 256 + (k0 - 256) + u * 8;
            fx4 f0 = *(const fx4*)s, f1 = *(const fx4*)(s + 4);
            u16x8 v;
            v[0]=f2b(f0[0]); v[1]=f2b(f0[1]); v[2]=f2b(f0[2]); v[3]=f2b(f0[3]);
            v[4]=f2b(f1[0]); v[5]=f2b(f1[1]); v[6]=f2b(f1[2]); v[7]=f2b(f1[3]);
            *(u16x8*)((char*)Al + c * 16) = v;
          }
        }
      } else if constexpr (MODE == 2) {
        const int node = rl;
        const float ct = cnt[node];
        const float rs = 1.f / fmaxf(ct, 1.f);
        const float* s = aggH_in + (size_t)node * 1024 + (k0 + u * 8);
        fx4 f0 = *(const fx4*)s, f1 = *(const fx4*)(s + 4);
        u16x8 v;
        v[0]=f2b(f0[0]*rs); v[1]=f2b(f0[1]*rs); v[2]=f2b(f0[2]*rs); v[3]=f2b(f0[3]*rs);
        v[4]=f2b(f1[0]*rs); v[5]=f2b(f1[1]*rs); v[6]=f2b(f1[2]*rs); v[7]=f2b(f1[3]*rs);
        *(u16x8*)((char*)Al + c * 16) = v;
      } else if constexpr (MODE == 3) {
        const int node = base + rl;
        if (k0 < 256)
          gload16(xb + (size_t)node * 256 + (k0 + u * 8), (char*)Al + c * 16);
        else
          gload16(agg2b_in + (size_t)node * 512 + (k0 - 256) + u * 8,
                  (char*)Al + c * 16);
      } else {
        gload16(A + (size_t)rl * K + (k0 + u * 8), (char*)Al + c * 16);
      }
    }
    __syncthreads();

    bf16x8 af[4], bfr[4];
    const int mb0 = wr * 64, nb0 = wc * 64;
#pragma unroll
    for (int i = 0; i < 4; i++)
      af[i] = *(const bf16x8*)(Al + (mb0 + i * 16 + lr) * 32 + lk * 8);
#pragma unroll
    for (int j = 0; j < 4; j++)
      bfr[j] = *(const bf16x8*)(Bl + (nb0 + j * 16 + lr) * 32 + lk * 8);
#pragma unroll
    for (int i = 0; i < 4; i++)
#pragma unroll
      for (int j = 0; j < 4; j++)
        acc[i][j] = __builtin_amdgcn_mfma_f32_16x16x32_bf16(af[i], bfr[j],
                                                            acc[i][j], 0, 0, 0);
    __syncthreads();
  }

  // Epilogue. C/D layout: col = lane&15, row = (lane>>4)*4 + reg  [m89]
  int dd[4][4];
  if constexpr (MODE == 1) {
#pragma unroll
    for (int i = 0; i < 4; i++) {
      const int m0 = tile_m * 128 + wr * 64 + i * 16 + lk * 4;
#pragma unroll
      for (int r = 0; r < 4; r++)
        dd[i][r] = (m0 + r < M) ? sdst[m0 + r] : -1;
    }
  }
#pragma unroll
  for (int j = 0; j < 4; j++) {
    const int n = tile_n * 128 + wc * 64 + j * 16 + lr;
    const float bj = bias[n];
    if constexpr (MODE == 1) {
      float pend = 0.f; int pdest = -1;
#pragma unroll
      for (int i = 0; i < 4; i++) {
#pragma unroll
        for (int r = 0; r < 4; r++) {
          const int d = dd[i][r];
          if (d >= 0) {
            float v = acc[i][j][r] + bj;
            v = v >= 0.f ? v : 0.01f * v;
            if (d == pdest) {
              pend += v;
            } else {
              if (pdest >= 0) atomicAdd(outf + (size_t)pdest * 1024 + n, pend);
              pdest = d; pend = v;
            }
          }
        }
      }
      if (pdest >= 0) atomicAdd(outf + (size_t)pdest * 1024 + n, pend);
    } else {
#pragma unroll
      for (int i = 0; i < 4; i++) {
        const int m0 = tile_m * 128 + wr * 64 + i * 16 + lk * 4;
#pragma unroll
        for (int r = 0; r < 4; r++) {
          const int m = m0 + r;
          if (m < M) {
            float v = acc[i][j][r];
            if constexpr (MODE == 2) {
              v += (cnt[m] > 0.f ? bj : 0.f);
              outb[(size_t)m * N + n] = f2b(v);
            } else if constexpr (MODE == 3) {
              v += bj;
              v = v >= 0.f ? v : 0.01f * v;
              outb[(size_t)m * N + n] = f2b(v);
            } else {
              outf[(size_t)(base + m) * N + n] = v + bj;
            }
          }
        }
      }
    }
  }
}

// ---------------------------------------------------------------------------
// Helper kernels
// ---------------------------------------------------------------------------
__global__ void fix_idx_k(const int* __restrict__ src, int* __restrict__ dst, int n2) {
  int i = blockIdx.x * blockDim.x + threadIdx.x;
  if (i >= n2) return;
  bool is64 = true;
#pragma unroll
  for (int p = 0; p < 16; ++p) is64 = is64 && (src[2 * p + 1] == 0);
  dst[i] = is64 ? src[2 * i] : src[i];
}

__global__ void cvt_f2b_k(const float* __restrict__ x, unsigned short* __restrict__ o,
                          long n4) {
  long i = (long)blockIdx.x * blockDim.x + threadIdx.x;
  if (i < n4) {
    fx4 f = *(const fx4*)(x + i * 4);
    u16x4 v; v[0]=f2b(f[0]); v[1]=f2b(f[1]); v[2]=f2b(f[2]); v[3]=f2b(f[3]);
    *(u16x4*)(o + i * 4) = v;
  }
}

// W[K][N] fp32 -> Wt[N][K] bf16
__global__ void cvt_w_k(const float* __restrict__ W, unsigned short* __restrict__ Wt,
                        int K, int N) {
  long i = (long)blockIdx.x * blockDim.x + threadIdx.x;
  if (i < (long)K * N) {
    int k = (int)(i / N), n = (int)(i % N);
    Wt[(size_t)n * K + k] = f2b(W[i]);
  }
}

__global__ void cnt_kk(const int* __restrict__ ecol, float* __restrict__ cnt, int E) {
  int i = blockIdx.x * blockDim.x + threadIdx.x;
  if (i < E) atomicAdd(cnt + ecol[i], 1.f);
}

// Single-block exclusive scan of (int)cnt -> pos  (Hillis-Steele per chunk)
__global__ __launch_bounds__(1024)
void scan_k(const float* __restrict__ cnt, int* __restrict__ pos, int Nn) {
  __shared__ int sdata[1024];
  __shared__ int carry;
  if (threadIdx.x == 0) carry = 0;
  __syncthreads();
  for (int bb = 0; bb < Nn; bb += 1024) {
    const int i = bb + threadIdx.x;
    const int v = (i < Nn) ? (int)cnt[i] : 0;
    sdata[threadIdx.x] = v;
    __syncthreads();
    for (int off = 1; off < 1024; off <<= 1) {
      int tv = (threadIdx.x >= off) ? sdata[threadIdx.x - off] : 0;
      __syncthreads();
      sdata[threadIdx.x] += tv;
      __syncthreads();
    }
    const int excl = sdata[threadIdx.x] - v + carry;
    if (i < Nn) pos[i] = excl;
    __syncthreads();
    if (threadIdx.x == 1023) carry += sdata[1023];
    __syncthreads();
  }
}

// counting-sort scatter: perm (sorted->orig), ssrc, sdst
__global__ void perm_k(const int* __restrict__ idx, int E, int* __restrict__ pos,
                       int* __restrict__ perm, int* __restrict__ ssrc,
                       int* __restrict__ sdst) {
  int e = blockIdx.x * blockDim.x + threadIdx.x;
  if (e >= E) return;
  const int d = idx[E + e];
  const int s = atomicAdd(pos + d, 1);
  perm[s] = e;
  ssrc[s] = idx[e];
  sdst[s] = d;
}

// ---------------------------------------------------------------------------
extern "C" void kernel_launch(void* const* d_in, const int* in_sizes, int n_in,
                              void* d_out, int out_size, void* d_ws, size_t ws_size,
                              hipStream_t stream)
{
  const float* x  = (const float*)d_in[0];
  const int* eraw = (const int*)d_in[1];
  const float* ea = (const float*)d_in[2];
  const float* W1 = (const float*)d_in[5];
  const float* b1 = (const float*)d_in[6];
  const float* W2 = (const float*)d_in[7];
  const float* b2 = (const float*)d_in[8];
  const float* W3 = (const float*)d_in[9];
  const float* b3 = (const float*)d_in[10];
  const float* W4 = (const float*)d_in[11];
  const float* b4 = (const float*)d_in[12];
  float* out = (float*)d_out;

  const int Nn = in_sizes[0] / 256;   // 50000
  const int E  = in_sizes[1] / 2;     // 500000

  // ---- workspace carve (256B-aligned bump allocator) ----
  char* p = (char*)d_ws;
  auto take = [&](size_t bytes) -> char* {
    char* r = p; p += (bytes + 255) & ~(size_t)255; return r;
  };
  unsigned short* W1t = (unsigned short*)take((size_t)512 * 1024 * 2);
  unsigned short* W2t = (unsigned short*)take((size_t)1024 * 512 * 2);
  unsigned short* W3t = (unsigned short*)take((size_t)768 * 1536 * 2);
  unsigned short* W4t = (unsigned short*)take((size_t)1536 * 256 * 2);
  int* idx  = (int*)take((size_t)2 * E * 4);
  float* cnt  = (float*)take((size_t)Nn * 4);
  float* aggH = (float*)take((size_t)Nn * 1024 * 4);      // layer-1 scatter-sum
  size_t zlen = (size_t)(p - (char*)cnt);                 // cnt+aggH zero region
  unsigned short* agg2b = (unsigned short*)take((size_t)Nn * 512 * 2);
  unsigned short* xb    = (unsigned short*)take((size_t)Nn * 256 * 2);
  int* pos  = (int*)take((size_t)Nn * 4);
  int* perm = (int*)take((size_t)E * 4);
  int* ssrc = (int*)take((size_t)E * 4);
  int* sdst = (int*)take((size_t)E * 4);

  long avail = (long)ws_size - (long)(p - (char*)d_ws);

  unsigned short* eab = nullptr;                          // optional bf16 edge_attr
  const long eab_bytes = (((long)E * 256 * 2) + 255) & ~255L;
  if (avail >= eab_bytes + 128 * 3072 + 1024) {
    eab = (unsigned short*)take((size_t)E * 256 * 2);
    avail -= eab_bytes;
  }
  long bandN = avail / 3072;  bandN &= ~127L;
  if (bandN > 50048) bandN = 50048;
  if (bandN < 128)   bandN = 128;
  unsigned short* H3 = (unsigned short*)take((size_t)bandN * 3072);

  hipMemsetAsync(cnt, 0, zlen, stream);
  fix_idx_k<<<(2 * E + 255) / 256, 256, 0, stream>>>(eraw, idx, 2 * E);
  cnt_kk<<<(E + 255) / 256, 256, 0, stream>>>(idx + E, cnt, E);   // dest counts
  scan_k<<<1, 1024, 0, stream>>>(cnt, pos, Nn);
  perm_k<<<(E + 255) / 256, 256, 0, stream>>>(idx, E, pos, perm, ssrc, sdst);
  cvt_f2b_k<<<(Nn * 64 + 255) / 256, 256, 0, stream>>>(x, xb, (long)Nn * 64);
  if (eab)
    cvt_f2b_k<<<(int)(((long)E * 64 + 255) / 256), 256, 0, stream>>>(ea, eab,
                                                                     (long)E * 64);
  cvt_w_k<<<(512 * 1024 + 255) / 256, 256, 0, stream>>>(W1, W1t, 512, 1024);
  cvt_w_k<<<(1024 * 512 + 255) / 256, 256, 0, stream>>>(W2, W2t, 1024, 512);
  cvt_w_k<<<(768 * 1536 + 255) / 256, 256, 0, stream>>>(W3, W3t, 768, 1536);
  cvt_w_k<<<(1536 * 256 + 255) / 256, 256, 0, stream>>>(W4, W4t, 1536, 256);

  // G1: edge layer-1 over dest-sorted edges + run-merged scatter into aggH
  const int mtE = (E + 127) / 128;
  if (eab)
    gemm_k<1, 512, 1024, true><<<dim3(8, mtE), 256, 0, stream>>>(
        nullptr, xb, eab, ea, nullptr, nullptr, nullptr, perm, ssrc, sdst,
        W1t, b1, aggH, nullptr, E, 0);
  else
    gemm_k<1, 512, 1024, false><<<dim3(8, mtE), 256, 0, stream>>>(
        nullptr, xb, nullptr, ea, nullptr, nullptr, nullptr, perm, ssrc, sdst,
        W1t, b1, aggH, nullptr, E, 0);

  // A2: agg2 = (aggH/max(cnt,1)) @ W2 + (cnt>0)*b2   [hoisted layer 2]
  const int mtN = (Nn + 127) / 128;
  gemm_k<2, 1024, 512, false><<<dim3(4, mtN), 256, 0, stream>>>(
      nullptr, nullptr, nullptr, nullptr, aggH, cnt, nullptr, nullptr, nullptr,
      nullptr, W2t, b2, nullptr, agg2b, Nn, 0);

  // node MLP, banded over nodes
  for (long base = 0; base < Nn; base += bandN) {
    long rem = Nn - base;
    int mb = (int)(rem < bandN ? rem : bandN);
    int mt = (mb + 127) / 128;
    gemm_k<3, 768, 1536, false><<<dim3(12, mt), 256, 0, stream>>>(
        nullptr, xb, nullptr, nullptr, nullptr, nullptr, agg2b, nullptr,
        nullptr, nullptr, W3t, b3, nullptr, H3, mb, (int)base);
    gemm_k<4, 1536, 256, false><<<dim3(2, mt), 256, 0, stream>>>(
        H3, nullptr, nullptr, nullptr, nullptr, nullptr, nullptr, nullptr,
        nullptr, nullptr, W4t, b4, out, nullptr, mb, (int)base);
  }
}